// Round 3
// baseline (482.335 us; speedup 1.0000x reference)
//
#include <hip/hip_runtime.h>
#include <math.h>

#define QMAXF 127.0f

struct Ptrs4 { const float* p[4]; };

__device__ __forceinline__ float qscale(float m) {
    // scale = where(max_abs > 0, max_abs/127, 1.0)
    return (m > 0.0f) ? (m / QMAXF) : 1.0f;
}

__device__ __forceinline__ float quant1(float x, float s) {
    // clip(round(x/s), -127, 127) * s   (round = half-to-even, matches jnp.round)
    float r = rintf(x / s);
    r = fminf(fmaxf(r, -QMAXF), QMAXF);
    return r * s;
}

// Block-wide max over all threads' v. All threads must call. sred must hold >=17 floats.
__device__ __forceinline__ float block_max_red(float v, float* sred) {
    #pragma unroll
    for (int off = 32; off > 0; off >>= 1)
        v = fmaxf(v, __shfl_down(v, off, 64));
    int wave = threadIdx.x >> 6;
    int lane = threadIdx.x & 63;
    __syncthreads();                 // protect sred reuse across calls
    if (lane == 0) sred[wave] = v;
    __syncthreads();
    if (threadIdx.x == 0) {
        int nw = blockDim.x >> 6;
        float m = sred[0];
        for (int i = 1; i < nw; ++i) m = fmaxf(m, sred[i]);
        sred[16] = m;
    }
    __syncthreads();
    return sred[16];
}

// Per-tensor quantize of the 4 values each thread holds (tensor = 4096 elems across block).
__device__ __forceinline__ void quant_vec4(float* a, float* sred) {
    float pm = 0.0f;
    #pragma unroll
    for (int i = 0; i < 4; ++i) pm = fmaxf(pm, fabsf(a[i]));
    float s = qscale(block_max_red(pm, sred));
    #pragma unroll
    for (int i = 0; i < 4; ++i) a[i] = quant1(a[i], s);
}

// ---------------------------------------------------------------------------
// Kernel 1: quantize concat = Q([h, x]) (block 0) and the 4 biases (blocks 1-4).
// Also zeroes the 4 atomic-max slots (ws is poisoned 0xAA before each launch).
// ---------------------------------------------------------------------------
__global__ __launch_bounds__(1024) void k_prep(
    const float* __restrict__ x, const float* __restrict__ h,
    Ptrs4 biases, float* __restrict__ concat_q, float* __restrict__ qb,
    unsigned* __restrict__ gmax)
{
    __shared__ float sred[17];
    int tid = threadIdx.x;
    if (blockIdx.x == 0) {
        if (tid < 4) gmax[tid] = 0u;
        float vals[8];
        float pm = 0.0f;
        #pragma unroll
        for (int i = 0; i < 8; ++i) {
            int idx = i * 1024 + tid;               // 0..8191
            float v = (i < 4) ? h[idx] : x[idx - 4096];  // concat = [h, inputs]
            vals[i] = v;
            pm = fmaxf(pm, fabsf(v));
        }
        float s = qscale(block_max_red(pm, sred));
        #pragma unroll
        for (int i = 0; i < 8; ++i) concat_q[i * 1024 + tid] = quant1(vals[i], s);
    } else {
        int g = blockIdx.x - 1;
        const float* __restrict__ b = biases.p[g];
        float vals[4];
        float pm = 0.0f;
        #pragma unroll
        for (int i = 0; i < 4; ++i) {
            float v = b[i * 1024 + tid];
            vals[i] = v;
            pm = fmaxf(pm, fabsf(v));
        }
        float s = qscale(block_max_red(pm, sred));
        #pragma unroll
        for (int i = 0; i < 4; ++i) qb[g * 4096 + i * 1024 + tid] = quant1(vals[i], s);
    }
}

// ---------------------------------------------------------------------------
// Kernel 2: GEMV partials. y[j] = sum_k xq[k] * W[k][j], W row-major [8192][4096].
// grid = (8 col-tiles, 32 k-chunks, 4 gates), block = 256.
// Each thread: 2 consecutive columns (float2), 256 k-iterations.
//
// Rounds 0/1: VGPR_Count 28-32 -> compiler sank every load to its use
// (~1 load in flight/wave, latency-bound, 21% HBM, 2-3% VALU).
// Round 2: each 16-load batch is followed by an empty asm volatile with a
// "memory" clobber. Loads cannot sink below it (asm may write memory) and
// the next batch cannot hoist above it -> all 16 issue as a block, and
// batch n+1's loads can still interleave with batch n's FMAs. ~16+ loads
// in flight per wave -> BW-bound.
// FMA order per column (k ascending) and the kc=32 partial layout are
// UNCHANGED -> bitwise-identical results.
// ---------------------------------------------------------------------------
__global__ __launch_bounds__(256, 4) void k_gemv(
    Ptrs4 wts, const float* __restrict__ xq, float* __restrict__ partials)
{
    int ct = blockIdx.x;   // 0..7   col tile (512 cols)
    int kc = blockIdx.y;   // 0..31  k chunk (256 rows)
    int g  = blockIdx.z;   // 0..3   gate
    const float* __restrict__ W = wts.p[g];
    int col0 = ct * 512 + threadIdx.x * 2;
    int k0 = kc * 256;
    const float* __restrict__ wrow = W + (size_t)k0 * 4096 + col0;
    const float* __restrict__ xp = xq + k0;

    float ax = 0.f, ay = 0.f;

    for (int kb = 0; kb < 256; kb += 16) {
        float2 b[16];   // fully unrolled, static indices -> VGPR-resident
        #pragma unroll
        for (int i = 0; i < 16; ++i)
            b[i] = *(const float2*)(wrow + (size_t)(kb + i) * 4096);
        // Compiler barrier: the 16 loads above must all issue before this
        // point (cannot sink past a potential asm memory write). Consumers
        // below then drain them with counted vmcnt waits.
        asm volatile("" ::: "memory");
        #pragma unroll
        for (int i = 0; i < 16; ++i) {
            float xv = xp[kb + i];   // wave-uniform -> scalar load
            ax = fmaf(xv, b[i].x, ax);
            ay = fmaf(xv, b[i].y, ay);
        }
    }

    float2 r; r.x = ax; r.y = ay;
    *(float2*)(partials + (size_t)(g * 32 + kc) * 4096 + col0) = r;
}

// ---------------------------------------------------------------------------
// Kernel 3: reduce 32 k-chunk partials per column; per-gate max|y| via atomicMax.
// grid = 64 blocks (gate = b>>4, colblock = b&15), block = 256.
// ---------------------------------------------------------------------------
__global__ __launch_bounds__(256) void k_reduce(
    const float* __restrict__ partials, float* __restrict__ y,
    unsigned* __restrict__ gmax)
{
    int g  = blockIdx.x >> 4;
    int cb = blockIdx.x & 15;
    int col = cb * 256 + threadIdx.x;
    float s = 0.0f;
    #pragma unroll 8
    for (int kc = 0; kc < 32; ++kc)
        s += partials[(size_t)(g * 32 + kc) * 4096 + col];
    y[g * 4096 + col] = s;

    float m = fabsf(s);
    #pragma unroll
    for (int off = 32; off > 0; off >>= 1)
        m = fmaxf(m, __shfl_down(m, off, 64));
    __shared__ float sm[4];
    int wave = threadIdx.x >> 6, lane = threadIdx.x & 63;
    if (lane == 0) sm[wave] = m;
    __syncthreads();
    if (threadIdx.x == 0) {
        float mm = fmaxf(fmaxf(sm[0], sm[1]), fmaxf(sm[2], sm[3]));
        atomicMax(gmax + g, __float_as_uint(mm));  // |y| >= 0: uint order == float order
    }
}

// ---------------------------------------------------------------------------
// Kernel 4: full quantized LSTM epilogue on one block (1024 thr x 4 elems/gate).
// gates: 0=f, 1=i, 2=c(candidate, tanh), 3=o
// ---------------------------------------------------------------------------
__global__ __launch_bounds__(1024) void k_epilogue(
    const float* __restrict__ y, const float* __restrict__ qb,
    const unsigned* __restrict__ gmax, const float* __restrict__ c,
    float* __restrict__ out)
{
    __shared__ float sred[17];
    int tid = threadIdx.x;
    float v[4][4];

    // q1 = Q(x@W); yb = q1 + Q(b)
    #pragma unroll
    for (int g = 0; g < 4; ++g) {
        float s = qscale(__uint_as_float(gmax[g]));
        #pragma unroll
        for (int i = 0; i < 4; ++i) {
            int col = i * 1024 + tid;
            v[g][i] = quant1(y[g * 4096 + col], s) + qb[g * 4096 + col];
        }
    }

    // q2 = Q(yb); act = tanh/sigmoid(q2)
    for (int g = 0; g < 4; ++g) {
        float pm = 0.0f;
        #pragma unroll
        for (int i = 0; i < 4; ++i) pm = fmaxf(pm, fabsf(v[g][i]));
        float s = qscale(block_max_red(pm, sred));
        #pragma unroll
        for (int i = 0; i < 4; ++i) {
            float q = quant1(v[g][i], s);
            v[g][i] = (g == 2) ? tanhf(q) : (1.0f / (1.0f + expf(-q)));
        }
    }

    // q3 = Q(act)  -> v[0]=zf, v[1]=zi, v[2]=z, v[3]=zo
    for (int g = 0; g < 4; ++g) {
        float pm = 0.0f;
        #pragma unroll
        for (int i = 0; i < 4; ++i) pm = fmaxf(pm, fabsf(v[g][i]));
        float s = qscale(block_max_red(pm, sred));
        #pragma unroll
        for (int i = 0; i < 4; ++i) v[g][i] = quant1(v[g][i], s);
    }

    // memory = Q(z * zi)
    float mem[4];
    #pragma unroll
    for (int i = 0; i < 4; ++i) mem[i] = v[2][i] * v[1][i];
    quant_vec4(mem, sred);

    // cf = Q(c * zf)
    float cf[4];
    #pragma unroll
    for (int i = 0; i < 4; ++i) cf[i] = c[i * 1024 + tid] * v[0][i];
    quant_vec4(cf, sred);

    // c_new = Q(cf + memory)
    float cn[4];
    #pragma unroll
    for (int i = 0; i < 4; ++i) cn[i] = cf[i] + mem[i];
    quant_vec4(cn, sred);

    // t = Q(tanh(c_new))
    float tc[4];
    #pragma unroll
    for (int i = 0; i < 4; ++i) tc[i] = tanhf(cn[i]);
    quant_vec4(tc, sred);

    // h_new = Q(zo * t)
    float hn[4];
    #pragma unroll
    for (int i = 0; i < 4; ++i) hn[i] = v[3][i] * tc[i];
    quant_vec4(hn, sred);
    #pragma unroll
    for (int i = 0; i < 4; ++i) out[i * 1024 + tid] = hn[i];
}

// ---------------------------------------------------------------------------
extern "C" void kernel_launch(void* const* d_in, const int* in_sizes, int n_in,
                              void* d_out, int out_size, void* d_ws, size_t ws_size,
                              hipStream_t stream) {
    const float* x = (const float*)d_in[0];   // inputs [1,4096]
    const float* c = (const float*)d_in[1];   // c      [1,4096]
    const float* h = (const float*)d_in[2];   // h      [1,4096]
    Ptrs4 wts, bs;
    wts.p[0] = (const float*)d_in[3];  bs.p[0] = (const float*)d_in[4];   // Wf
    wts.p[1] = (const float*)d_in[5];  bs.p[1] = (const float*)d_in[6];   // Wi
    wts.p[2] = (const float*)d_in[7];  bs.p[2] = (const float*)d_in[8];   // Wc
    wts.p[3] = (const float*)d_in[9];  bs.p[3] = (const float*)d_in[10];  // Wo

    float* ws = (float*)d_ws;
    float* partials = ws;                  // 4*32*4096 = 524288 floats (2 MiB)
    float* concat_q = ws + 524288;         // 8192 floats
    float* qb       = ws + 532480;         // 4*4096 = 16384 floats
    float* yv       = ws + 548864;         // 4*4096 = 16384 floats
    unsigned* gmax  = (unsigned*)(ws + 565248);  // 4 uints

    hipLaunchKernelGGL(k_prep,     dim3(5),        dim3(1024), 0, stream,
                       x, h, bs, concat_q, qb, gmax);
    hipLaunchKernelGGL(k_gemv,     dim3(8, 32, 4), dim3(256),  0, stream,
                       wts, concat_q, partials);
    hipLaunchKernelGGL(k_reduce,   dim3(64),       dim3(256),  0, stream,
                       partials, yv, gmax);
    hipLaunchKernelGGL(k_epilogue, dim3(1),        dim3(1024), 0, stream,
                       yv, qb, gmax, c, (float*)d_out);
}

// Round 4
// 477.804 us; speedup vs baseline: 1.0095x; 1.0095x over previous
//
#include <hip/hip_runtime.h>
#include <math.h>

#define QMAXF 127.0f

struct Ptrs4 { const float* p[4]; };

__device__ __forceinline__ float qscale(float m) {
    // scale = where(max_abs > 0, max_abs/127, 1.0)
    return (m > 0.0f) ? (m / QMAXF) : 1.0f;
}

__device__ __forceinline__ float quant1(float x, float s) {
    // clip(round(x/s), -127, 127) * s   (round = half-to-even, matches jnp.round)
    float r = rintf(x / s);
    r = fminf(fmaxf(r, -QMAXF), QMAXF);
    return r * s;
}

// Block-wide max over all threads' v. All threads must call. sred must hold >=17 floats.
__device__ __forceinline__ float block_max_red(float v, float* sred) {
    #pragma unroll
    for (int off = 32; off > 0; off >>= 1)
        v = fmaxf(v, __shfl_down(v, off, 64));
    int wave = threadIdx.x >> 6;
    int lane = threadIdx.x & 63;
    __syncthreads();                 // protect sred reuse across calls
    if (lane == 0) sred[wave] = v;
    __syncthreads();
    if (threadIdx.x == 0) {
        int nw = blockDim.x >> 6;
        float m = sred[0];
        for (int i = 1; i < nw; ++i) m = fmaxf(m, sred[i]);
        sred[16] = m;
    }
    __syncthreads();
    return sred[16];
}

// Per-tensor quantize of the 4 values each thread holds (tensor = 4096 elems across block).
__device__ __forceinline__ void quant_vec4(float* a, float* sred) {
    float pm = 0.0f;
    #pragma unroll
    for (int i = 0; i < 4; ++i) pm = fmaxf(pm, fabsf(a[i]));
    float s = qscale(block_max_red(pm, sred));
    #pragma unroll
    for (int i = 0; i < 4; ++i) a[i] = quant1(a[i], s);
}

// ---------------------------------------------------------------------------
// Kernel 1: quantize concat = Q([h, x]) (block 0) and the 4 biases (blocks 1-4).
// Also zeroes the 4 atomic-max slots (ws is poisoned 0xAA before each launch).
// ---------------------------------------------------------------------------
__global__ __launch_bounds__(1024) void k_prep(
    const float* __restrict__ x, const float* __restrict__ h,
    Ptrs4 biases, float* __restrict__ concat_q, float* __restrict__ qb,
    unsigned* __restrict__ gmax)
{
    __shared__ float sred[17];
    int tid = threadIdx.x;
    if (blockIdx.x == 0) {
        if (tid < 4) gmax[tid] = 0u;
        float vals[8];
        float pm = 0.0f;
        #pragma unroll
        for (int i = 0; i < 8; ++i) {
            int idx = i * 1024 + tid;               // 0..8191
            float v = (i < 4) ? h[idx] : x[idx - 4096];  // concat = [h, inputs]
            vals[i] = v;
            pm = fmaxf(pm, fabsf(v));
        }
        float s = qscale(block_max_red(pm, sred));
        #pragma unroll
        for (int i = 0; i < 8; ++i) concat_q[i * 1024 + tid] = quant1(vals[i], s);
    } else {
        int g = blockIdx.x - 1;
        const float* __restrict__ b = biases.p[g];
        float vals[4];
        float pm = 0.0f;
        #pragma unroll
        for (int i = 0; i < 4; ++i) {
            float v = b[i * 1024 + tid];
            vals[i] = v;
            pm = fmaxf(pm, fabsf(v));
        }
        float s = qscale(block_max_red(pm, sred));
        #pragma unroll
        for (int i = 0; i < 4; ++i) qb[g * 4096 + i * 1024 + tid] = quant1(vals[i], s);
    }
}

// ---------------------------------------------------------------------------
// Kernel 2: GEMV partials. y[j] = sum_k xq[k] * W[k][j], W row-major [8192][4096].
// grid = (8 col-tiles, 32 k-chunks, 4 gates), block = 256.
// Each thread: 2 consecutive columns (float2), 256 k-iterations.
//
// History: rounds 0/1/3 all ended with VGPR_Count 24-32 -> the scheduler
// interleaved load->fma->load->fma (register-only FMAs hoist past asm
// "memory" fences, rule #18) -> ~1-2 loads in flight/wave, latency-bound
// at 3.3 TB/s delivered (161 us).
// Round 4: __builtin_amdgcn_sched_barrier(0) between the 16-load batch
// (weights AND x-scalars) and the FMA block. Mask 0 = NOTHING crosses, in
// either direction, and it survives post-RA scheduling. All 16 loads must
// issue before any consumer -> 16-deep vmcnt pipeline per wave -> BW-bound.
// Success tell: VGPR_Count >= 48. If it's back at ~24-32 the fence was
// dropped and the next step is global_load_lds LDS staging.
// FMA order per column (k ascending) and the kc=32 partial layout are
// UNCHANGED -> bitwise-identical results.
// ---------------------------------------------------------------------------
__global__ __launch_bounds__(256, 4) void k_gemv(
    Ptrs4 wts, const float* __restrict__ xq, float* __restrict__ partials)
{
    int ct = blockIdx.x;   // 0..7   col tile (512 cols)
    int kc = blockIdx.y;   // 0..31  k chunk (256 rows)
    int g  = blockIdx.z;   // 0..3   gate
    const float* __restrict__ W = wts.p[g];
    int col0 = ct * 512 + threadIdx.x * 2;
    int k0 = kc * 256;
    const float* __restrict__ wrow = W + (size_t)k0 * 4096 + col0;
    const float* __restrict__ xp = xq + k0;

    float ax = 0.f, ay = 0.f;

    for (int kb = 0; kb < 256; kb += 16) {
        float2 b[16];    // fully unrolled, static indices -> VGPR-resident
        float xv[16];
        #pragma unroll
        for (int i = 0; i < 16; ++i)
            b[i] = *(const float2*)(wrow + (size_t)(kb + i) * 4096);
        #pragma unroll
        for (int i = 0; i < 16; ++i)
            xv[i] = xp[kb + i];   // wave-uniform -> s_load (lgkmcnt)
        // Hard scheduling fence: no instruction may cross, either direction.
        // All 16 vector loads + the scalar x loads are issued above; the
        // FMA block below drains them with counted vmcnt/lgkmcnt waits.
        __builtin_amdgcn_sched_barrier(0);
        #pragma unroll
        for (int i = 0; i < 16; ++i) {
            ax = fmaf(xv[i], b[i].x, ax);
            ay = fmaf(xv[i], b[i].y, ay);
        }
    }

    float2 r; r.x = ax; r.y = ay;
    *(float2*)(partials + (size_t)(g * 32 + kc) * 4096 + col0) = r;
}

// ---------------------------------------------------------------------------
// Kernel 3: reduce 32 k-chunk partials per column; per-gate max|y| via atomicMax.
// grid = 64 blocks (gate = b>>4, colblock = b&15), block = 256.
// ---------------------------------------------------------------------------
__global__ __launch_bounds__(256) void k_reduce(
    const float* __restrict__ partials, float* __restrict__ y,
    unsigned* __restrict__ gmax)
{
    int g  = blockIdx.x >> 4;
    int cb = blockIdx.x & 15;
    int col = cb * 256 + threadIdx.x;
    float s = 0.0f;
    #pragma unroll 8
    for (int kc = 0; kc < 32; ++kc)
        s += partials[(size_t)(g * 32 + kc) * 4096 + col];
    y[g * 4096 + col] = s;

    float m = fabsf(s);
    #pragma unroll
    for (int off = 32; off > 0; off >>= 1)
        m = fmaxf(m, __shfl_down(m, off, 64));
    __shared__ float sm[4];
    int wave = threadIdx.x >> 6, lane = threadIdx.x & 63;
    if (lane == 0) sm[wave] = m;
    __syncthreads();
    if (threadIdx.x == 0) {
        float mm = fmaxf(fmaxf(sm[0], sm[1]), fmaxf(sm[2], sm[3]));
        atomicMax(gmax + g, __float_as_uint(mm));  // |y| >= 0: uint order == float order
    }
}

// ---------------------------------------------------------------------------
// Kernel 4: full quantized LSTM epilogue on one block (1024 thr x 4 elems/gate).
// gates: 0=f, 1=i, 2=c(candidate, tanh), 3=o
// ---------------------------------------------------------------------------
__global__ __launch_bounds__(1024) void k_epilogue(
    const float* __restrict__ y, const float* __restrict__ qb,
    const unsigned* __restrict__ gmax, const float* __restrict__ c,
    float* __restrict__ out)
{
    __shared__ float sred[17];
    int tid = threadIdx.x;
    float v[4][4];

    // q1 = Q(x@W); yb = q1 + Q(b)
    #pragma unroll
    for (int g = 0; g < 4; ++g) {
        float s = qscale(__uint_as_float(gmax[g]));
        #pragma unroll
        for (int i = 0; i < 4; ++i) {
            int col = i * 1024 + tid;
            v[g][i] = quant1(y[g * 4096 + col], s) + qb[g * 4096 + col];
        }
    }

    // q2 = Q(yb); act = tanh/sigmoid(q2)
    for (int g = 0; g < 4; ++g) {
        float pm = 0.0f;
        #pragma unroll
        for (int i = 0; i < 4; ++i) pm = fmaxf(pm, fabsf(v[g][i]));
        float s = qscale(block_max_red(pm, sred));
        #pragma unroll
        for (int i = 0; i < 4; ++i) {
            float q = quant1(v[g][i], s);
            v[g][i] = (g == 2) ? tanhf(q) : (1.0f / (1.0f + expf(-q)));
        }
    }

    // q3 = Q(act)  -> v[0]=zf, v[1]=zi, v[2]=z, v[3]=zo
    for (int g = 0; g < 4; ++g) {
        float pm = 0.0f;
        #pragma unroll
        for (int i = 0; i < 4; ++i) pm = fmaxf(pm, fabsf(v[g][i]));
        float s = qscale(block_max_red(pm, sred));
        #pragma unroll
        for (int i = 0; i < 4; ++i) v[g][i] = quant1(v[g][i], s);
    }

    // memory = Q(z * zi)
    float mem[4];
    #pragma unroll
    for (int i = 0; i < 4; ++i) mem[i] = v[2][i] * v[1][i];
    quant_vec4(mem, sred);

    // cf = Q(c * zf)
    float cf[4];
    #pragma unroll
    for (int i = 0; i < 4; ++i) cf[i] = c[i * 1024 + tid] * v[0][i];
    quant_vec4(cf, sred);

    // c_new = Q(cf + memory)
    float cn[4];
    #pragma unroll
    for (int i = 0; i < 4; ++i) cn[i] = cf[i] + mem[i];
    quant_vec4(cn, sred);

    // t = Q(tanh(c_new))
    float tc[4];
    #pragma unroll
    for (int i = 0; i < 4; ++i) tc[i] = tanhf(cn[i]);
    quant_vec4(tc, sred);

    // h_new = Q(zo * t)
    float hn[4];
    #pragma unroll
    for (int i = 0; i < 4; ++i) hn[i] = v[3][i] * tc[i];
    quant_vec4(hn, sred);
    #pragma unroll
    for (int i = 0; i < 4; ++i) out[i * 1024 + tid] = hn[i];
}

// ---------------------------------------------------------------------------
extern "C" void kernel_launch(void* const* d_in, const int* in_sizes, int n_in,
                              void* d_out, int out_size, void* d_ws, size_t ws_size,
                              hipStream_t stream) {
    const float* x = (const float*)d_in[0];   // inputs [1,4096]
    const float* c = (const float*)d_in[1];   // c      [1,4096]
    const float* h = (const float*)d_in[2];   // h      [1,4096]
    Ptrs4 wts, bs;
    wts.p[0] = (const float*)d_in[3];  bs.p[0] = (const float*)d_in[4];   // Wf
    wts.p[1] = (const float*)d_in[5];  bs.p[1] = (const float*)d_in[6];   // Wi
    wts.p[2] = (const float*)d_in[7];  bs.p[2] = (const float*)d_in[8];   // Wc
    wts.p[3] = (const float*)d_in[9];  bs.p[3] = (const float*)d_in[10];  // Wo

    float* ws = (float*)d_ws;
    float* partials = ws;                  // 4*32*4096 = 524288 floats (2 MiB)
    float* concat_q = ws + 524288;         // 8192 floats
    float* qb       = ws + 532480;         // 4*4096 = 16384 floats
    float* yv       = ws + 548864;         // 4*4096 = 16384 floats
    unsigned* gmax  = (unsigned*)(ws + 565248);  // 4 uints

    hipLaunchKernelGGL(k_prep,     dim3(5),        dim3(1024), 0, stream,
                       x, h, bs, concat_q, qb, gmax);
    hipLaunchKernelGGL(k_gemv,     dim3(8, 32, 4), dim3(256),  0, stream,
                       wts, concat_q, partials);
    hipLaunchKernelGGL(k_reduce,   dim3(64),       dim3(256),  0, stream,
                       partials, yv, gmax);
    hipLaunchKernelGGL(k_epilogue, dim3(1),        dim3(1024), 0, stream,
                       yv, qb, gmax, c, (float*)d_out);
}

// Round 5
// 461.810 us; speedup vs baseline: 1.0444x; 1.0346x over previous
//
#include <hip/hip_runtime.h>
#include <math.h>

#define QMAXF 127.0f

struct Ptrs4 { const float* p[4]; };

__device__ __forceinline__ float qscale(float m) {
    // scale = where(max_abs > 0, max_abs/127, 1.0)
    return (m > 0.0f) ? (m / QMAXF) : 1.0f;
}

__device__ __forceinline__ float quant1(float x, float s) {
    // clip(round(x/s), -127, 127) * s   (round = half-to-even, matches jnp.round)
    float r = rintf(x / s);
    r = fminf(fmaxf(r, -QMAXF), QMAXF);
    return r * s;
}

// Block-wide max over all threads' v. All threads must call. sred must hold >=17 floats.
__device__ __forceinline__ float block_max_red(float v, float* sred) {
    #pragma unroll
    for (int off = 32; off > 0; off >>= 1)
        v = fmaxf(v, __shfl_down(v, off, 64));
    int wave = threadIdx.x >> 6;
    int lane = threadIdx.x & 63;
    __syncthreads();                 // protect sred reuse across calls
    if (lane == 0) sred[wave] = v;
    __syncthreads();
    if (threadIdx.x == 0) {
        int nw = blockDim.x >> 6;
        float m = sred[0];
        for (int i = 1; i < nw; ++i) m = fmaxf(m, sred[i]);
        sred[16] = m;
    }
    __syncthreads();
    return sred[16];
}

// Per-tensor quantize of the 4 values each thread holds (tensor = 4096 elems across block).
__device__ __forceinline__ void quant_vec4(float* a, float* sred) {
    float pm = 0.0f;
    #pragma unroll
    for (int i = 0; i < 4; ++i) pm = fmaxf(pm, fabsf(a[i]));
    float s = qscale(block_max_red(pm, sred));
    #pragma unroll
    for (int i = 0; i < 4; ++i) a[i] = quant1(a[i], s);
}

// ---------------------------------------------------------------------------
// Kernel 1: quantize concat = Q([h, x]) (block 0) and the 4 biases (blocks 1-4).
// Also zeroes the 4 atomic-max slots (ws is poisoned 0xAA before each launch).
// ---------------------------------------------------------------------------
__global__ __launch_bounds__(1024) void k_prep(
    const float* __restrict__ x, const float* __restrict__ h,
    Ptrs4 biases, float* __restrict__ concat_q, float* __restrict__ qb,
    unsigned* __restrict__ gmax)
{
    __shared__ float sred[17];
    int tid = threadIdx.x;
    if (blockIdx.x == 0) {
        if (tid < 4) gmax[tid] = 0u;
        float vals[8];
        float pm = 0.0f;
        #pragma unroll
        for (int i = 0; i < 8; ++i) {
            int idx = i * 1024 + tid;               // 0..8191
            float v = (i < 4) ? h[idx] : x[idx - 4096];  // concat = [h, inputs]
            vals[i] = v;
            pm = fmaxf(pm, fabsf(v));
        }
        float s = qscale(block_max_red(pm, sred));
        #pragma unroll
        for (int i = 0; i < 8; ++i) concat_q[i * 1024 + tid] = quant1(vals[i], s);
    } else {
        int g = blockIdx.x - 1;
        const float* __restrict__ b = biases.p[g];
        float vals[4];
        float pm = 0.0f;
        #pragma unroll
        for (int i = 0; i < 4; ++i) {
            float v = b[i * 1024 + tid];
            vals[i] = v;
            pm = fmaxf(pm, fabsf(v));
        }
        float s = qscale(block_max_red(pm, sred));
        #pragma unroll
        for (int i = 0; i < 4; ++i) qb[g * 4096 + i * 1024 + tid] = quant1(vals[i], s);
    }
}

// ---------------------------------------------------------------------------
// Kernel 2: GEMV partials. y[j] = sum_k xq[k] * W[k][j], W row-major [8192][4096].
// grid = (8 col-tiles, 32 k-chunks, 4 gates), block = 256 (4 waves).
// Each thread: 2 consecutive columns, 256 k-iterations.
//
// History: rounds 0-4 all ended with VGPR_Count 24-32 regardless of source
// structure (reg double-buffer, asm memory fence, sched_barrier(0)) -> the
// compiler always collapses VGPR-destination load batches to ~1 in flight
// per wave -> latency-bound at 3.4 TB/s delivered (155-163 us, 21% HBM).
// Round 5: global_load_lds. Async global->LDS loads have NO destination
// VGPR, so the collapse is structurally impossible. Double-buffered LDS
// tile (2 x [8 rows][512 cols] = 32 KB): stage batch kb+8 while computing
// batch kb from LDS; one __syncthreads per iteration (the compiler's
// vmcnt(0)-before-barrier drain is the synchronization mechanism).
// LDS dest is linear in lane order (global_load_lds requirement, m104).
// FMA order per column (k ascending 0..255) and the kc=32 partial layout
// are UNCHANGED -> bitwise-identical results.
// ---------------------------------------------------------------------------
__global__ __launch_bounds__(256, 4) void k_gemv(
    Ptrs4 wts, const float* __restrict__ xq, float* __restrict__ partials)
{
    __shared__ float buf[2][8 * 512];   // 2 x 16 KB

    int ct = blockIdx.x;   // 0..7   col tile (512 cols)
    int kc = blockIdx.y;   // 0..31  k chunk (256 rows)
    int g  = blockIdx.z;   // 0..3   gate
    const float* __restrict__ W = wts.p[g];
    int tid  = threadIdx.x;
    int wave = tid >> 6;
    int lane = tid & 63;
    int k0 = kc * 256;
    const float* __restrict__ wbase = W + (size_t)k0 * 4096 + ct * 512;
    const float* __restrict__ xp = xq + k0;

    // Stage 8 rows x 512 cols (16 KB) of W into lbuf.
    // 16 wave-instructions x 1 KB (64 lanes x 16 B); 4 per wave.
    // LDS layout: row-major [8][512], written linearly (uniform base +
    // lane*16B per HW rule) -> buf[row][half*256 + lane*4 .. +3].
    auto stage = [&](const float* wsrc, float* lbuf) {
        #pragma unroll
        for (int j = 0; j < 4; ++j) {
            int t = wave * 4 + j;          // 0..15
            int row = t >> 1, half = t & 1;
            const float* src = wsrc + (size_t)row * 4096 + half * 256 + lane * 4;
            float* dst = lbuf + row * 512 + half * 256;   // wave-uniform
            __builtin_amdgcn_global_load_lds(
                (const __attribute__((address_space(1))) void*)src,
                (__attribute__((address_space(3))) void*)dst, 16, 0, 0);
        }
    };

    float ax = 0.f, ay = 0.f;

    stage(wbase, buf[0]);                  // prologue: batch 0
    __syncthreads();                       // drains vmcnt(0) before s_barrier
    int cur = 0;

    for (int kb = 0; kb < 256; kb += 8) {
        if (kb + 8 < 256)
            stage(wbase + (size_t)(kb + 8) * 4096, buf[cur ^ 1]);
        #pragma unroll
        for (int r = 0; r < 8; ++r) {
            float xv = xp[kb + r];         // wave-uniform -> scalar load
            float2 wv = *(const float2*)&buf[cur][r * 512 + tid * 2];
            ax = fmaf(xv, wv.x, ax);
            ay = fmaf(xv, wv.y, ay);
        }
        __syncthreads();                   // waits staged loads + LDS reads
        cur ^= 1;
    }

    int col0 = ct * 512 + tid * 2;
    float2 r; r.x = ax; r.y = ay;
    *(float2*)(partials + (size_t)(g * 32 + kc) * 4096 + col0) = r;
}

// ---------------------------------------------------------------------------
// Kernel 3: reduce 32 k-chunk partials per column; per-gate max|y| via atomicMax.
// grid = 64 blocks (gate = b>>4, colblock = b&15), block = 256.
// ---------------------------------------------------------------------------
__global__ __launch_bounds__(256) void k_reduce(
    const float* __restrict__ partials, float* __restrict__ y,
    unsigned* __restrict__ gmax)
{
    int g  = blockIdx.x >> 4;
    int cb = blockIdx.x & 15;
    int col = cb * 256 + threadIdx.x;
    float s = 0.0f;
    #pragma unroll 8
    for (int kc = 0; kc < 32; ++kc)
        s += partials[(size_t)(g * 32 + kc) * 4096 + col];
    y[g * 4096 + col] = s;

    float m = fabsf(s);
    #pragma unroll
    for (int off = 32; off > 0; off >>= 1)
        m = fmaxf(m, __shfl_down(m, off, 64));
    __shared__ float sm[4];
    int wave = threadIdx.x >> 6, lane = threadIdx.x & 63;
    if (lane == 0) sm[wave] = m;
    __syncthreads();
    if (threadIdx.x == 0) {
        float mm = fmaxf(fmaxf(sm[0], sm[1]), fmaxf(sm[2], sm[3]));
        atomicMax(gmax + g, __float_as_uint(mm));  // |y| >= 0: uint order == float order
    }
}

// ---------------------------------------------------------------------------
// Kernel 4: full quantized LSTM epilogue on one block (1024 thr x 4 elems/gate).
// gates: 0=f, 1=i, 2=c(candidate, tanh), 3=o
// ---------------------------------------------------------------------------
__global__ __launch_bounds__(1024) void k_epilogue(
    const float* __restrict__ y, const float* __restrict__ qb,
    const unsigned* __restrict__ gmax, const float* __restrict__ c,
    float* __restrict__ out)
{
    __shared__ float sred[17];
    int tid = threadIdx.x;
    float v[4][4];

    // q1 = Q(x@W); yb = q1 + Q(b)
    #pragma unroll
    for (int g = 0; g < 4; ++g) {
        float s = qscale(__uint_as_float(gmax[g]));
        #pragma unroll
        for (int i = 0; i < 4; ++i) {
            int col = i * 1024 + tid;
            v[g][i] = quant1(y[g * 4096 + col], s) + qb[g * 4096 + col];
        }
    }

    // q2 = Q(yb); act = tanh/sigmoid(q2)
    for (int g = 0; g < 4; ++g) {
        float pm = 0.0f;
        #pragma unroll
        for (int i = 0; i < 4; ++i) pm = fmaxf(pm, fabsf(v[g][i]));
        float s = qscale(block_max_red(pm, sred));
        #pragma unroll
        for (int i = 0; i < 4; ++i) {
            float q = quant1(v[g][i], s);
            v[g][i] = (g == 2) ? tanhf(q) : (1.0f / (1.0f + expf(-q)));
        }
    }

    // q3 = Q(act)  -> v[0]=zf, v[1]=zi, v[2]=z, v[3]=zo
    for (int g = 0; g < 4; ++g) {
        float pm = 0.0f;
        #pragma unroll
        for (int i = 0; i < 4; ++i) pm = fmaxf(pm, fabsf(v[g][i]));
        float s = qscale(block_max_red(pm, sred));
        #pragma unroll
        for (int i = 0; i < 4; ++i) v[g][i] = quant1(v[g][i], s);
    }

    // memory = Q(z * zi)
    float mem[4];
    #pragma unroll
    for (int i = 0; i < 4; ++i) mem[i] = v[2][i] * v[1][i];
    quant_vec4(mem, sred);

    // cf = Q(c * zf)
    float cf[4];
    #pragma unroll
    for (int i = 0; i < 4; ++i) cf[i] = c[i * 1024 + tid] * v[0][i];
    quant_vec4(cf, sred);

    // c_new = Q(cf + memory)
    float cn[4];
    #pragma unroll
    for (int i = 0; i < 4; ++i) cn[i] = cf[i] + mem[i];
    quant_vec4(cn, sred);

    // t = Q(tanh(c_new))
    float tc[4];
    #pragma unroll
    for (int i = 0; i < 4; ++i) tc[i] = tanhf(cn[i]);
    quant_vec4(tc, sred);

    // h_new = Q(zo * t)
    float hn[4];
    #pragma unroll
    for (int i = 0; i < 4; ++i) hn[i] = v[3][i] * tc[i];
    quant_vec4(hn, sred);
    #pragma unroll
    for (int i = 0; i < 4; ++i) out[i * 1024 + tid] = hn[i];
}

// ---------------------------------------------------------------------------
extern "C" void kernel_launch(void* const* d_in, const int* in_sizes, int n_in,
                              void* d_out, int out_size, void* d_ws, size_t ws_size,
                              hipStream_t stream) {
    const float* x = (const float*)d_in[0];   // inputs [1,4096]
    const float* c = (const float*)d_in[1];   // c      [1,4096]
    const float* h = (const float*)d_in[2];   // h      [1,4096]
    Ptrs4 wts, bs;
    wts.p[0] = (const float*)d_in[3];  bs.p[0] = (const float*)d_in[4];   // Wf
    wts.p[1] = (const float*)d_in[5];  bs.p[1] = (const float*)d_in[6];   // Wi
    wts.p[2] = (const float*)d_in[7];  bs.p[2] = (const float*)d_in[8];   // Wc
    wts.p[3] = (const float*)d_in[9];  bs.p[3] = (const float*)d_in[10];  // Wo

    float* ws = (float*)d_ws;
    float* partials = ws;                  // 4*32*4096 = 524288 floats (2 MiB)
    float* concat_q = ws + 524288;         // 8192 floats
    float* qb       = ws + 532480;         // 4*4096 = 16384 floats
    float* yv       = ws + 548864;         // 4*4096 = 16384 floats
    unsigned* gmax  = (unsigned*)(ws + 565248);  // 4 uints

    hipLaunchKernelGGL(k_prep,     dim3(5),        dim3(1024), 0, stream,
                       x, h, bs, concat_q, qb, gmax);
    hipLaunchKernelGGL(k_gemv,     dim3(8, 32, 4), dim3(256),  0, stream,
                       wts, concat_q, partials);
    hipLaunchKernelGGL(k_reduce,   dim3(64),       dim3(256),  0, stream,
                       partials, yv, gmax);
    hipLaunchKernelGGL(k_epilogue, dim3(1),        dim3(1024), 0, stream,
                       yv, qb, gmax, c, (float*)d_out);
}